// Round 15
// baseline (139.349 us; speedup 1.0000x reference)
//
#include <hip/hip_runtime.h>
#include <hip/hip_bf16.h>
#include <stdint.h>

typedef float f32x4 __attribute__((ext_vector_type(4)));
typedef __bf16 bf16x8 __attribute__((ext_vector_type(8)));
typedef unsigned short u16;

#define MFMA16(a, b, c) __builtin_amdgcn_mfma_f32_16x16x32_bf16((a), (b), (c), 0, 0, 0)

__device__ __forceinline__ u16 f2bf(float f) {
  union { float f; uint32_t u; } v; v.f = f;
  uint32_t u = v.u;
  return (u16)((u + 0x7fffu + ((u >> 16) & 1u)) >> 16);
}
__device__ __forceinline__ float bf2f(u16 h) {
  union { uint32_t u; float f; } v; v.u = ((uint32_t)h) << 16;
  return v.f;
}

// ---------------- kernel 0: weights -> bf16 transposed [c][k] -----------------
__global__ void prep_weights_kernel(const float* __restrict__ Wq, const float* __restrict__ Wk,
                                    const float* __restrict__ Wv, const float* __restrict__ Wp,
                                    u16* __restrict__ Wt) {
  int w = blockIdx.x;
  const float* W = (w == 0) ? Wq : (w == 1) ? Wk : (w == 2) ? Wv : Wp;
  int t = blockIdx.y * 256 + threadIdx.x;  // 0..16383
  int c = t >> 7, k = t & 127;
  Wt[(w * 128 + c) * 128 + k] = f2bf(W[k * 128 + c]);
}

// ---------------- FUSED kernel v4: fused3 + BURST weight prefetch ------------
// Same dataflow as fused3 (110us): wave-private x staging (no barrier-1),
// K overwrites own x rows, V^T, in-block vmean, fixed-max softmax attention,
// fused1 epilogue. ONE change: the QKV and out-proj GEMMs load their weight
// B-fragments in 16-frag BURSTS (16KB/wave in flight; VGPR is free at 1
// block/CU) with per-ct transient accumulators, instead of 24 interleaved
// load->MFMA groups that each expose L2 latency at 2 waves/SIMD.
__global__ __launch_bounds__(512, 1) void fused4_kernel(
    const u16* __restrict__ Wt, const float* __restrict__ x,
    const int* __restrict__ mask, const float* __restrict__ rel,
    const float* __restrict__ bq, const float* __restrict__ bk,
    const float* __restrict__ bv, const float* __restrict__ bp,
    const float* __restrict__ ln_g, const float* __restrict__ ln_b,
    float* __restrict__ out) {
  __shared__ u16 KX[256][136];        // x (per-wave) -> K               69632 B
  __shared__ u16 V_lds[128][264];     // V^T [d][t]                      67584 B
  __shared__ u16 P_lds[8][32][40];    // per-wave repack slices          20480 B
  __shared__ float rel_lds[511];      //                                  2044 B
  __shared__ float vmean_lds[128];    //                                   512 B -> 160252 B
  const int tid = threadIdx.x;
  const int n = blockIdx.x;
  const int bb = n / 100, rr = n - bb * 100;
  const int* mrow = mask + bb * 256;
  if (tid < 511) rel_lds[tid] = rel[tid];
  const int l = tid & 63, wv = tid >> 6, l15 = l & 15, l4 = l >> 4;
  const int tt0 = wv * 32;  // this wave's 32 q-rows

  bf16x8 wbuf[16];
  // first Q-frag burst (cts 0..3) — independent of x, flies during staging
#pragma unroll
  for (int c = 0; c < 4; ++c)
#pragma unroll
    for (int ks = 0; ks < 4; ++ks)
      wbuf[c * 4 + ks] = *(const bf16x8*)(Wt + (size_t)(c * 16 + l15) * 128 + ks * 32 + l4 * 8);

  {  // WAVE-PRIVATE stage: own 32 rows of x -> KX[tt0..tt0+32) (no barrier)
    int row = tt0 + (l >> 1), half = (l & 1) * 64;
    const float* src = x + ((size_t)(n * 256 + row)) * 128 + half;
    u16* dst = &KX[row][half];
#pragma unroll
    for (int j = 0; j < 16; ++j) {
      float4 f = ((const float4*)src)[j];
      dst[j * 4 + 0] = f2bf(f.x); dst[j * 4 + 1] = f2bf(f.y);
      dst[j * 4 + 2] = f2bf(f.z); dst[j * 4 + 3] = f2bf(f.w);
    }
  }
  int ttg[2][4], qm[2][4];
#pragma unroll
  for (int g = 0; g < 2; ++g)
#pragma unroll
    for (int rg = 0; rg < 4; ++rg) {
      ttg[g][rg] = tt0 + g * 16 + 4 * l4 + rg;
      qm[g][rg] = mrow[ttg[g][rg]];
    }

  // ---- per-wave reads of OWN x rows (A-frags + packed residual) ----
  bf16x8 af[2][4];
#pragma unroll
  for (int g = 0; g < 2; ++g)
#pragma unroll
    for (int ks = 0; ks < 4; ++ks)
      af[g][ks] = *(const bf16x8*)&KX[tt0 + g * 16 + l15][ks * 32 + l4 * 8];
  uint32_t xres[2][4][4];  // x[ttg[g][rg]][ct*16+l15], ct=2c|2c+1 packed
#pragma unroll
  for (int g = 0; g < 2; ++g)
#pragma unroll
    for (int rg = 0; rg < 4; ++rg) {
      const u16* xr = &KX[tt0 + g * 16 + 4 * l4 + rg][0];
#pragma unroll
      for (int c = 0; c < 4; ++c)
        xres[g][rg][c] = (uint32_t)xr[c * 32 + l15] | ((uint32_t)xr[c * 32 + 16 + l15] << 16);
    }

  const float scale = 0.088388347648318447f;  // 1/sqrt(128)
  // ---- Q = x @ Wq + bq -> qa[] via P-slice repack (burst-prefetched) ----
  bf16x8 qa[2][4];
#pragma unroll 1
  for (int h = 0; h < 2; ++h) {
    if (h == 1) {  // second burst (cts 4..7); first was issued pre-staging
#pragma unroll
      for (int c = 0; c < 4; ++c)
#pragma unroll
        for (int ks = 0; ks < 4; ++ks)
          wbuf[c * 4 + ks] = *(const bf16x8*)(Wt + (size_t)((4 + c) * 16 + l15) * 128 + ks * 32 + l4 * 8);
    }
#pragma unroll
    for (int c = 0; c < 4; ++c) {
      const int ct = h * 4 + c;
      f32x4 aq[2] = {f32x4{0.f, 0.f, 0.f, 0.f}, f32x4{0.f, 0.f, 0.f, 0.f}};
#pragma unroll
      for (int ks = 0; ks < 4; ++ks)
#pragma unroll
        for (int g = 0; g < 2; ++g)
          aq[g] = MFMA16(af[g][ks], wbuf[c * 4 + ks], aq[g]);
      float bqv = bq[ct * 16 + l15];
#pragma unroll
      for (int g = 0; g < 2; ++g)
#pragma unroll
        for (int rg = 0; rg < 4; ++rg)
          P_lds[wv][g * 16 + 4 * l4 + rg][(ct & 1) * 16 + l15] = f2bf((aq[g][rg] + bqv) * scale);
      if (ct & 1) {
#pragma unroll
        for (int g = 0; g < 2; ++g)
          qa[g][ct >> 1] = *(const bf16x8*)&P_lds[wv][g * 16 + l15][l4 * 8];
      }
    }
  }
  // ---- K = x @ Wk + bk -> overwrite OWN x rows in KX (burst-prefetched) ----
#pragma unroll 1
  for (int h = 0; h < 2; ++h) {
#pragma unroll
    for (int c = 0; c < 4; ++c)
#pragma unroll
      for (int ks = 0; ks < 4; ++ks)
        wbuf[c * 4 + ks] = *(const bf16x8*)(Wt + (size_t)(128 + (h * 4 + c) * 16 + l15) * 128 + ks * 32 + l4 * 8);
#pragma unroll
    for (int c = 0; c < 4; ++c) {
      const int ct = h * 4 + c;
      f32x4 ak[2] = {f32x4{0.f, 0.f, 0.f, 0.f}, f32x4{0.f, 0.f, 0.f, 0.f}};
#pragma unroll
      for (int ks = 0; ks < 4; ++ks)
#pragma unroll
        for (int g = 0; g < 2; ++g)
          ak[g] = MFMA16(af[g][ks], wbuf[c * 4 + ks], ak[g]);
      float bkv = bk[ct * 16 + l15];
#pragma unroll
      for (int g = 0; g < 2; ++g)
#pragma unroll
        for (int rg = 0; rg < 4; ++rg)
          KX[tt0 + g * 16 + 4 * l4 + rg][ct * 16 + l15] = f2bf(ak[g][rg] + bkv);
    }
  }
  // ---- V = x @ Wv + bv -> V^T region (burst-prefetched) ----
#pragma unroll 1
  for (int h = 0; h < 2; ++h) {
#pragma unroll
    for (int c = 0; c < 4; ++c)
#pragma unroll
      for (int ks = 0; ks < 4; ++ks)
        wbuf[c * 4 + ks] = *(const bf16x8*)(Wt + (size_t)(256 + (h * 4 + c) * 16 + l15) * 128 + ks * 32 + l4 * 8);
#pragma unroll
    for (int c = 0; c < 4; ++c) {
      const int ct = h * 4 + c;
      f32x4 av[2] = {f32x4{0.f, 0.f, 0.f, 0.f}, f32x4{0.f, 0.f, 0.f, 0.f}};
#pragma unroll
      for (int ks = 0; ks < 4; ++ks)
#pragma unroll
        for (int g = 0; g < 2; ++g)
          av[g] = MFMA16(af[g][ks], wbuf[c * 4 + ks], av[g]);
      float bvv = bv[ct * 16 + l15];
#pragma unroll
      for (int g = 0; g < 2; ++g)
#pragma unroll
        for (int rg = 0; rg < 4; ++rg)
          V_lds[ct * 16 + l15][tt0 + g * 16 + 4 * l4 + rg] = f2bf(av[g][rg] + bvv);
    }
  }
  __syncthreads();  // barrier 2: K/V complete
  {  // in-block vmean over V^T rows
    int d = tid >> 2, seg = tid & 3;
    const u16* vr = &V_lds[d][seg * 64];
    float s = 0.f;
#pragma unroll
    for (int j = 0; j < 8; ++j) {
      uint4 u = *(const uint4*)(vr + j * 8);
      s += bf2f((u16)(u.x & 0xffff)) + bf2f((u16)(u.x >> 16));
      s += bf2f((u16)(u.y & 0xffff)) + bf2f((u16)(u.y >> 16));
      s += bf2f((u16)(u.z & 0xffff)) + bf2f((u16)(u.z >> 16));
      s += bf2f((u16)(u.w & 0xffff)) + bf2f((u16)(u.w >> 16));
    }
    s += __shfl_xor(s, 1); s += __shfl_xor(s, 2);
    if (seg == 0) vmean_lds[d] = s * (1.f / 256.f);
  }
  float lsum[2][4]; f32x4 cacc[2][8];
#pragma unroll
  for (int g = 0; g < 2; ++g)
#pragma unroll
    for (int rg = 0; rg < 4; ++rg) lsum[g][rg] = 0.f;
#pragma unroll
  for (int g = 0; g < 2; ++g)
#pragma unroll
    for (int ct = 0; ct < 8; ++ct) cacc[g][ct] = f32x4{0.f, 0.f, 0.f, 0.f};
  __syncthreads();  // barrier 3: vmean ready; no more block syncs

  // ---- attention: fixed-max softmax, 32 rows/wave ----
  const int nkv = (wv >> 1) + 1;
  for (int kv = 0; kv < nkv; ++kv) {
    const int s0 = kv * 64;
    f32x4 sacc[2][4];
#pragma unroll
    for (int g = 0; g < 2; ++g)
#pragma unroll
      for (int ct = 0; ct < 4; ++ct) sacc[g][ct] = f32x4{0.f, 0.f, 0.f, 0.f};
#pragma unroll
    for (int ct = 0; ct < 4; ++ct)
#pragma unroll
      for (int ks = 0; ks < 4; ++ks) {
        bf16x8 bfr = *(const bf16x8*)&KX[s0 + ct * 16 + l15][ks * 32 + l4 * 8];
#pragma unroll
        for (int g = 0; g < 2; ++g) sacc[g][ct] = MFMA16(qa[g][ks], bfr, sacc[g][ct]);
      }
    int km[4];
#pragma unroll
    for (int ct = 0; ct < 4; ++ct) km[ct] = mrow[s0 + ct * 16 + l15];
    float p[2][4][4];
#pragma unroll
    for (int g = 0; g < 2; ++g)
#pragma unroll
      for (int ct = 0; ct < 4; ++ct) {
        const int ss = s0 + ct * 16 + l15;
#pragma unroll
        for (int rg = 0; rg < 4; ++rg) {
          float sv = sacc[g][ct][rg] + rel_lds[ttg[g][rg] - ss + 255];
          bool msk = (ss > ttg[g][rg]) | (km[ct] == 0) | (qm[g][rg] == 0);
          sv = msk ? -1.0e9f : sv;
          float pv = __expf(sv);  // masked -> exactly 0
          p[g][ct][rg] = pv;
          lsum[g][rg] += pv;
        }
      }
#pragma unroll
    for (int c = 0; c < 2; ++c) {
#pragma unroll
      for (int g = 0; g < 2; ++g)
#pragma unroll
        for (int c2 = 0; c2 < 2; ++c2)
#pragma unroll
          for (int rg = 0; rg < 4; ++rg)
            P_lds[wv][g * 16 + 4 * l4 + rg][c2 * 16 + l15] = f2bf(p[g][2 * c + c2][rg]);
      bf16x8 pa[2];
#pragma unroll
      for (int g = 0; g < 2; ++g)
        pa[g] = *(const bf16x8*)&P_lds[wv][g * 16 + l15][l4 * 8];
#pragma unroll
      for (int ct = 0; ct < 8; ++ct) {
        bf16x8 vb = *(const bf16x8*)&V_lds[ct * 16 + l15][s0 + c * 32 + l4 * 8];
#pragma unroll
        for (int g = 0; g < 2; ++g) cacc[g][ct] = MFMA16(pa[g], vb, cacc[g][ct]);
      }
    }
  }
  float li[2][4];
#pragma unroll
  for (int g = 0; g < 2; ++g)
#pragma unroll
    for (int rg = 0; rg < 4; ++rg) {
      float rs = lsum[g][rg];
#pragma unroll
      for (int off = 1; off < 16; off <<= 1) rs += __shfl_xor(rs, off);
      li[g][rg] = rs;
    }
  // ---- ctx -> out-proj (burst-prefetched) -> residual+LN -> scatter ----
  bf16x8 ca[2][4];
#pragma unroll
  for (int q = 0; q < 4; ++q) {
#pragma unroll
    for (int g = 0; g < 2; ++g)
#pragma unroll
      for (int c2 = 0; c2 < 2; ++c2) {
        int ct = 2 * q + c2;
        float vm = vmean_lds[ct * 16 + l15];
#pragma unroll
        for (int rg = 0; rg < 4; ++rg) {
          float cval = cacc[g][ct][rg] / li[g][rg];
          cval = (qm[g][rg] == 0) ? vm : cval;
          P_lds[wv][g * 16 + 4 * l4 + rg][c2 * 16 + l15] = f2bf(cval);
        }
      }
#pragma unroll
    for (int g = 0; g < 2; ++g)
      ca[g][q] = *(const bf16x8*)&P_lds[wv][g * 16 + l15][l4 * 8];
  }
  f32x4 oacc[2][8];
#pragma unroll
  for (int g = 0; g < 2; ++g)
#pragma unroll
    for (int ct = 0; ct < 8; ++ct) oacc[g][ct] = f32x4{0.f, 0.f, 0.f, 0.f};
#pragma unroll 1
  for (int h = 0; h < 2; ++h) {
#pragma unroll
    for (int c = 0; c < 4; ++c)
#pragma unroll
      for (int ks = 0; ks < 4; ++ks)
        wbuf[c * 4 + ks] = *(const bf16x8*)(Wt + (size_t)(384 + (h * 4 + c) * 16 + l15) * 128 + ks * 32 + l4 * 8);
#pragma unroll
    for (int c = 0; c < 4; ++c) {
      const int ct = h * 4 + c;
#pragma unroll
      for (int ks = 0; ks < 4; ++ks)
#pragma unroll
        for (int g = 0; g < 2; ++g)
          oacc[g][ct] = MFMA16(ca[g][ks], wbuf[c * 4 + ks], oacc[g][ct]);
    }
  }
  float bpv[8], gv[8], bt[8];
#pragma unroll
  for (int ct = 0; ct < 8; ++ct) {
    int d = ct * 16 + l15;
    bpv[ct] = bp[d]; gv[ct] = ln_g[d]; bt[ct] = ln_b[d];
  }
#pragma unroll
  for (int g = 0; g < 2; ++g)
#pragma unroll
    for (int rg = 0; rg < 4; ++rg) {
      const int tg = ttg[g][rg];
      float yv[8], sum = 0.f, sq = 0.f;
#pragma unroll
      for (int ct = 0; ct < 8; ++ct) {
        uint32_t pr = xres[g][rg][ct >> 1];
        u16 xh = (ct & 1) ? (u16)(pr >> 16) : (u16)(pr & 0xffff);
        float v = oacc[g][ct][rg] + bpv[ct] + bf2f(xh);
        yv[ct] = v; sum += v; sq += v * v;
      }
#pragma unroll
      for (int off = 1; off < 16; off <<= 1) { sum += __shfl_xor(sum, off); sq += __shfl_xor(sq, off); }
      float mean = sum * (1.f / 128.f);
      float var = sq * (1.f / 128.f) - mean * mean;
      float rstd = rsqrtf(var + 1e-5f);
      float* orow = out + (((size_t)(bb * 256 + tg)) * 100 + rr) * 128;
#pragma unroll
      for (int ct = 0; ct < 8; ++ct)
        orow[ct * 16 + l15] = (yv[ct] - mean) * rstd * gv[ct] + bt[ct];
    }
}

extern "C" void kernel_launch(void* const* d_in, const int* in_sizes, int n_in,
                              void* d_out, int out_size, void* d_ws, size_t ws_size,
                              hipStream_t stream) {
  const float* x    = (const float*)d_in[0];
  const int*   mask = (const int*)d_in[1];
  const float* Wq   = (const float*)d_in[2];
  const float* bq   = (const float*)d_in[3];
  const float* Wk   = (const float*)d_in[4];
  const float* bk   = (const float*)d_in[5];
  const float* Wv   = (const float*)d_in[6];
  const float* bv   = (const float*)d_in[7];
  const float* Wp   = (const float*)d_in[8];
  const float* bp   = (const float*)d_in[9];
  const float* ln_g = (const float*)d_in[10];
  const float* ln_b = (const float*)d_in[11];
  const float* rel  = (const float*)d_in[12];
  float* out = (float*)d_out;
  u16* Wt = (u16*)d_ws;  // [4][128][128] bf16 transposed — only workspace use

  hipLaunchKernelGGL(prep_weights_kernel, dim3(4, 64), dim3(256), 0, stream, Wq, Wk, Wv, Wp, Wt);
  hipLaunchKernelGGL(fused4_kernel, dim3(400), dim3(512), 0, stream,
                     Wt, x, mask, rel, bq, bk, bv, bp, ln_g, ln_b, out);
}

// Round 16
// 101.904 us; speedup vs baseline: 1.3675x; 1.3675x over previous
//
#include <hip/hip_runtime.h>
#include <hip/hip_bf16.h>
#include <stdint.h>

typedef float f32x4 __attribute__((ext_vector_type(4)));
typedef __bf16 bf16x8 __attribute__((ext_vector_type(8)));
typedef unsigned short u16;

#define MFMA16(a, b, c) __builtin_amdgcn_mfma_f32_16x16x32_bf16((a), (b), (c), 0, 0, 0)

__device__ __forceinline__ u16 f2bf(float f) {
  union { float f; uint32_t u; } v; v.f = f;
  uint32_t u = v.u;
  return (u16)((u + 0x7fffu + ((u >> 16) & 1u)) >> 16);
}
__device__ __forceinline__ float bf2f(u16 h) {
  union { uint32_t u; float f; } v; v.u = ((uint32_t)h) << 16;
  return v.f;
}

// ---------------- kernel 0: weights -> bf16 transposed [c][k] -----------------
__global__ void prep_weights_kernel(const float* __restrict__ Wq, const float* __restrict__ Wk,
                                    const float* __restrict__ Wv, const float* __restrict__ Wp,
                                    u16* __restrict__ Wt) {
  int w = blockIdx.x;
  const float* W = (w == 0) ? Wq : (w == 1) ? Wk : (w == 2) ? Wv : Wp;
  int t = blockIdx.y * 256 + threadIdx.x;  // 0..16383
  int c = t >> 7, k = t & 127;
  Wt[(w * 128 + c) * 128 + k] = f2bf(W[k * 128 + c]);
}

// ---------------- FUSED kernel v5: fused3 + spill-safe ping-pong prefetch ----
// fused3 dataflow unchanged (wave-private staging, no barrier-1, K overwrites
// own x rows, V^T, in-block vmean, fixed-max softmax, fused1 epilogue).
// Change: weight B-frags use a 2-deep ping-pong (bA/bB, 32 VGPR peak — fused4's
// 64-reg burst spilled: WRITE_SIZE 58->161MB) chained ACROSS GEMMs (Q tail
// prefetches K head, K tail prefetches V head). launch_bounds(512,2) grants
// the allocator 256 VGPR for our LDS-forced 2 waves/SIMD.
__global__ __launch_bounds__(512, 2) void fused5_kernel(
    const u16* __restrict__ Wt, const float* __restrict__ x,
    const int* __restrict__ mask, const float* __restrict__ rel,
    const float* __restrict__ bq, const float* __restrict__ bk,
    const float* __restrict__ bv, const float* __restrict__ bp,
    const float* __restrict__ ln_g, const float* __restrict__ ln_b,
    float* __restrict__ out) {
  __shared__ u16 KX[256][136];        // x (per-wave) -> K               69632 B
  __shared__ u16 V_lds[128][264];     // V^T [d][t]                      67584 B
  __shared__ u16 P_lds[8][32][40];    // per-wave repack slices          20480 B
  __shared__ float rel_lds[511];      //                                  2044 B
  __shared__ float vmean_lds[128];    //                                   512 B -> 160252 B
  const int tid = threadIdx.x;
  const int n = blockIdx.x;
  const int bb = n / 100, rr = n - bb * 100;
  const int* mrow = mask + bb * 256;
  if (tid < 511) rel_lds[tid] = rel[tid];
  const int l = tid & 63, wv = tid >> 6, l15 = l & 15, l4 = l >> 4;
  const int tt0 = wv * 32;  // this wave's 32 q-rows

#define LOADW4(buf, ROWB)                                                  \
  do {                                                                     \
    const u16* _wp = Wt + (size_t)((ROWB) + l15) * 128 + l4 * 8;           \
    buf[0] = *(const bf16x8*)(_wp);                                        \
    buf[1] = *(const bf16x8*)(_wp + 32);                                   \
    buf[2] = *(const bf16x8*)(_wp + 64);                                   \
    buf[3] = *(const bf16x8*)(_wp + 96);                                   \
  } while (0)

  bf16x8 bA[4], bB[4];
  LOADW4(bA, 0);  // Q ct0 — independent of x, flies under staging

  {  // WAVE-PRIVATE stage: own 32 rows of x -> KX[tt0..tt0+32) (no barrier)
    int row = tt0 + (l >> 1), half = (l & 1) * 64;
    const float* src = x + ((size_t)(n * 256 + row)) * 128 + half;
    u16* dst = &KX[row][half];
#pragma unroll
    for (int j = 0; j < 16; ++j) {
      float4 f = ((const float4*)src)[j];
      dst[j * 4 + 0] = f2bf(f.x); dst[j * 4 + 1] = f2bf(f.y);
      dst[j * 4 + 2] = f2bf(f.z); dst[j * 4 + 3] = f2bf(f.w);
    }
  }
  int ttg[2][4], qm[2][4];
#pragma unroll
  for (int g = 0; g < 2; ++g)
#pragma unroll
    for (int rg = 0; rg < 4; ++rg) {
      ttg[g][rg] = tt0 + g * 16 + 4 * l4 + rg;
      qm[g][rg] = mrow[ttg[g][rg]];
    }

  // ---- per-wave reads of OWN x rows (A-frags + packed residual) ----
  bf16x8 af[2][4];
#pragma unroll
  for (int g = 0; g < 2; ++g)
#pragma unroll
    for (int ks = 0; ks < 4; ++ks)
      af[g][ks] = *(const bf16x8*)&KX[tt0 + g * 16 + l15][ks * 32 + l4 * 8];
  uint32_t xres[2][4][4];  // x[ttg[g][rg]][ct*16+l15], ct=2c|2c+1 packed
#pragma unroll
  for (int g = 0; g < 2; ++g)
#pragma unroll
    for (int rg = 0; rg < 4; ++rg) {
      const u16* xr = &KX[tt0 + g * 16 + 4 * l4 + rg][0];
#pragma unroll
      for (int c = 0; c < 4; ++c)
        xres[g][rg][c] = (uint32_t)xr[c * 32 + l15] | ((uint32_t)xr[c * 32 + 16 + l15] << 16);
    }

  const float scale = 0.088388347648318447f;  // 1/sqrt(128)
  f32x4 t0, t1;  // transient per-ct accumulators
#define MF8(buf)                                                           \
  do {                                                                     \
    t0 = f32x4{0.f, 0.f, 0.f, 0.f}; t1 = f32x4{0.f, 0.f, 0.f, 0.f};       \
    _Pragma("unroll") for (int ks = 0; ks < 4; ++ks) {                     \
      t0 = MFMA16(af[0][ks], buf[ks], t0);                                 \
      t1 = MFMA16(af[1][ks], buf[ks], t1);                                 \
    }                                                                      \
  } while (0)

  // ---- Q = x @ Wq + bq -> qa[] via P-slice repack (ping-pong prefetch) ----
  bf16x8 qa[2][4];
#define QSTORE(CT)                                                         \
  do {                                                                     \
    float bqv = bq[(CT) * 16 + l15];                                       \
    _Pragma("unroll") for (int rg = 0; rg < 4; ++rg) {                     \
      P_lds[wv][4 * l4 + rg][((CT) & 1) * 16 + l15] = f2bf((t0[rg] + bqv) * scale); \
      P_lds[wv][16 + 4 * l4 + rg][((CT) & 1) * 16 + l15] = f2bf((t1[rg] + bqv) * scale); \
    }                                                                      \
    if ((CT) & 1) {                                                        \
      qa[0][(CT) >> 1] = *(const bf16x8*)&P_lds[wv][l15][l4 * 8];          \
      qa[1][(CT) >> 1] = *(const bf16x8*)&P_lds[wv][16 + l15][l4 * 8];     \
    }                                                                      \
  } while (0)
  LOADW4(bB, 16);
  MF8(bA); LOADW4(bA, 2 * 16);        QSTORE(0);
  MF8(bB); LOADW4(bB, 3 * 16);        QSTORE(1);
  MF8(bA); LOADW4(bA, 4 * 16);        QSTORE(2);
  MF8(bB); LOADW4(bB, 5 * 16);        QSTORE(3);
  MF8(bA); LOADW4(bA, 6 * 16);        QSTORE(4);
  MF8(bB); LOADW4(bB, 7 * 16);        QSTORE(5);
  MF8(bA); LOADW4(bA, 128 + 0);       QSTORE(6);  // prefetch K ct0
  MF8(bB); LOADW4(bB, 128 + 16);      QSTORE(7);  // prefetch K ct1

  // ---- K = x @ Wk + bk -> overwrite OWN x rows in KX ----
#define KSTORE(CT)                                                         \
  do {                                                                     \
    float bkv = bk[(CT) * 16 + l15];                                       \
    _Pragma("unroll") for (int rg = 0; rg < 4; ++rg) {                     \
      KX[tt0 + 4 * l4 + rg][(CT) * 16 + l15] = f2bf(t0[rg] + bkv);         \
      KX[tt0 + 16 + 4 * l4 + rg][(CT) * 16 + l15] = f2bf(t1[rg] + bkv);    \
    }                                                                      \
  } while (0)
  MF8(bA); LOADW4(bA, 128 + 2 * 16);  KSTORE(0);
  MF8(bB); LOADW4(bB, 128 + 3 * 16);  KSTORE(1);
  MF8(bA); LOADW4(bA, 128 + 4 * 16);  KSTORE(2);
  MF8(bB); LOADW4(bB, 128 + 5 * 16);  KSTORE(3);
  MF8(bA); LOADW4(bA, 128 + 6 * 16);  KSTORE(4);
  MF8(bB); LOADW4(bB, 128 + 7 * 16);  KSTORE(5);
  MF8(bA); LOADW4(bA, 256 + 0);       KSTORE(6);  // prefetch V ct0
  MF8(bB); LOADW4(bB, 256 + 16);      KSTORE(7);  // prefetch V ct1

  // ---- V = x @ Wv + bv -> V^T region ----
#define VSTORE(CT)                                                         \
  do {                                                                     \
    float bvv = bv[(CT) * 16 + l15];                                       \
    _Pragma("unroll") for (int rg = 0; rg < 4; ++rg) {                     \
      V_lds[(CT) * 16 + l15][tt0 + 4 * l4 + rg] = f2bf(t0[rg] + bvv);      \
      V_lds[(CT) * 16 + l15][tt0 + 16 + 4 * l4 + rg] = f2bf(t1[rg] + bvv); \
    }                                                                      \
  } while (0)
  MF8(bA); LOADW4(bA, 256 + 2 * 16);  VSTORE(0);
  MF8(bB); LOADW4(bB, 256 + 3 * 16);  VSTORE(1);
  MF8(bA); LOADW4(bA, 256 + 4 * 16);  VSTORE(2);
  MF8(bB); LOADW4(bB, 256 + 5 * 16);  VSTORE(3);
  MF8(bA); LOADW4(bA, 256 + 6 * 16);  VSTORE(4);
  MF8(bB); LOADW4(bB, 256 + 7 * 16);  VSTORE(5);
  MF8(bA);                            VSTORE(6);
  MF8(bB);                            VSTORE(7);

  __syncthreads();  // barrier 2: K/V complete
  {  // in-block vmean over V^T rows
    int d = tid >> 2, seg = tid & 3;
    const u16* vr = &V_lds[d][seg * 64];
    float s = 0.f;
#pragma unroll
    for (int j = 0; j < 8; ++j) {
      uint4 u = *(const uint4*)(vr + j * 8);
      s += bf2f((u16)(u.x & 0xffff)) + bf2f((u16)(u.x >> 16));
      s += bf2f((u16)(u.y & 0xffff)) + bf2f((u16)(u.y >> 16));
      s += bf2f((u16)(u.z & 0xffff)) + bf2f((u16)(u.z >> 16));
      s += bf2f((u16)(u.w & 0xffff)) + bf2f((u16)(u.w >> 16));
    }
    s += __shfl_xor(s, 1); s += __shfl_xor(s, 2);
    if (seg == 0) vmean_lds[d] = s * (1.f / 256.f);
  }
  float lsum[2][4]; f32x4 cacc[2][8];
#pragma unroll
  for (int g = 0; g < 2; ++g)
#pragma unroll
    for (int rg = 0; rg < 4; ++rg) lsum[g][rg] = 0.f;
#pragma unroll
  for (int g = 0; g < 2; ++g)
#pragma unroll
    for (int ct = 0; ct < 8; ++ct) cacc[g][ct] = f32x4{0.f, 0.f, 0.f, 0.f};
  __syncthreads();  // barrier 3: vmean ready; no more block syncs

  // ---- attention: fixed-max softmax, 32 rows/wave ----
  const int nkv = (wv >> 1) + 1;
  for (int kv = 0; kv < nkv; ++kv) {
    const int s0 = kv * 64;
    f32x4 sacc[2][4];
#pragma unroll
    for (int g = 0; g < 2; ++g)
#pragma unroll
      for (int ct = 0; ct < 4; ++ct) sacc[g][ct] = f32x4{0.f, 0.f, 0.f, 0.f};
#pragma unroll
    for (int ct = 0; ct < 4; ++ct)
#pragma unroll
      for (int ks = 0; ks < 4; ++ks) {
        bf16x8 bfr = *(const bf16x8*)&KX[s0 + ct * 16 + l15][ks * 32 + l4 * 8];
#pragma unroll
        for (int g = 0; g < 2; ++g) sacc[g][ct] = MFMA16(qa[g][ks], bfr, sacc[g][ct]);
      }
    int km[4];
#pragma unroll
    for (int ct = 0; ct < 4; ++ct) km[ct] = mrow[s0 + ct * 16 + l15];
    float p[2][4][4];
#pragma unroll
    for (int g = 0; g < 2; ++g)
#pragma unroll
      for (int ct = 0; ct < 4; ++ct) {
        const int ss = s0 + ct * 16 + l15;
#pragma unroll
        for (int rg = 0; rg < 4; ++rg) {
          float sv = sacc[g][ct][rg] + rel_lds[ttg[g][rg] - ss + 255];
          bool msk = (ss > ttg[g][rg]) | (km[ct] == 0) | (qm[g][rg] == 0);
          sv = msk ? -1.0e9f : sv;
          float pv = __expf(sv);  // masked -> exactly 0
          p[g][ct][rg] = pv;
          lsum[g][rg] += pv;
        }
      }
#pragma unroll
    for (int c = 0; c < 2; ++c) {
#pragma unroll
      for (int g = 0; g < 2; ++g)
#pragma unroll
        for (int c2 = 0; c2 < 2; ++c2)
#pragma unroll
          for (int rg = 0; rg < 4; ++rg)
            P_lds[wv][g * 16 + 4 * l4 + rg][c2 * 16 + l15] = f2bf(p[g][2 * c + c2][rg]);
      bf16x8 pa[2];
#pragma unroll
      for (int g = 0; g < 2; ++g)
        pa[g] = *(const bf16x8*)&P_lds[wv][g * 16 + l15][l4 * 8];
#pragma unroll
      for (int ct = 0; ct < 8; ++ct) {
        bf16x8 vb = *(const bf16x8*)&V_lds[ct * 16 + l15][s0 + c * 32 + l4 * 8];
#pragma unroll
        for (int g = 0; g < 2; ++g) cacc[g][ct] = MFMA16(pa[g], vb, cacc[g][ct]);
      }
    }
  }
  float li[2][4];
#pragma unroll
  for (int g = 0; g < 2; ++g)
#pragma unroll
    for (int rg = 0; rg < 4; ++rg) {
      float rs = lsum[g][rg];
#pragma unroll
      for (int off = 1; off < 16; off <<= 1) rs += __shfl_xor(rs, off);
      li[g][rg] = rs;
    }
  // ---- ctx -> out-proj (ping-pong) -> residual+LN -> scatter ----
  bf16x8 ca[2][4];
#pragma unroll
  for (int q = 0; q < 4; ++q) {
#pragma unroll
    for (int g = 0; g < 2; ++g)
#pragma unroll
      for (int c2 = 0; c2 < 2; ++c2) {
        int ct = 2 * q + c2;
        float vm = vmean_lds[ct * 16 + l15];
#pragma unroll
        for (int rg = 0; rg < 4; ++rg) {
          float cval = cacc[g][ct][rg] / li[g][rg];
          cval = (qm[g][rg] == 0) ? vm : cval;
          P_lds[wv][g * 16 + 4 * l4 + rg][c2 * 16 + l15] = f2bf(cval);
        }
      }
#pragma unroll
    for (int g = 0; g < 2; ++g)
      ca[g][q] = *(const bf16x8*)&P_lds[wv][g * 16 + l15][l4 * 8];
  }
  f32x4 oacc[2][8];
#define OACC(CT)                                                           \
  do {                                                                     \
    oacc[0][CT] = t0; oacc[1][CT] = t1;                                    \
  } while (0)
#define MF8C(buf)                                                          \
  do {                                                                     \
    t0 = f32x4{0.f, 0.f, 0.f, 0.f}; t1 = f32x4{0.f, 0.f, 0.f, 0.f};       \
    _Pragma("unroll") for (int ks = 0; ks < 4; ++ks) {                     \
      t0 = MFMA16(ca[0][ks], buf[ks], t0);                                 \
      t1 = MFMA16(ca[1][ks], buf[ks], t1);                                 \
    }                                                                      \
  } while (0)
  LOADW4(bA, 384 + 0);
  LOADW4(bB, 384 + 16);
  MF8C(bA); LOADW4(bA, 384 + 2 * 16); OACC(0);
  MF8C(bB); LOADW4(bB, 384 + 3 * 16); OACC(1);
  MF8C(bA); LOADW4(bA, 384 + 4 * 16); OACC(2);
  MF8C(bB); LOADW4(bB, 384 + 5 * 16); OACC(3);
  MF8C(bA); LOADW4(bA, 384 + 6 * 16); OACC(4);
  MF8C(bB); LOADW4(bB, 384 + 7 * 16); OACC(5);
  MF8C(bA);                           OACC(6);
  MF8C(bB);                           OACC(7);

  float bpv[8], gv[8], bt[8];
#pragma unroll
  for (int ct = 0; ct < 8; ++ct) {
    int d = ct * 16 + l15;
    bpv[ct] = bp[d]; gv[ct] = ln_g[d]; bt[ct] = ln_b[d];
  }
#pragma unroll
  for (int g = 0; g < 2; ++g)
#pragma unroll
    for (int rg = 0; rg < 4; ++rg) {
      const int tg = ttg[g][rg];
      float yv[8], sum = 0.f, sq = 0.f;
#pragma unroll
      for (int ct = 0; ct < 8; ++ct) {
        uint32_t pr = xres[g][rg][ct >> 1];
        u16 xh = (ct & 1) ? (u16)(pr >> 16) : (u16)(pr & 0xffff);
        float v = oacc[g][ct][rg] + bpv[ct] + bf2f(xh);
        yv[ct] = v; sum += v; sq += v * v;
      }
#pragma unroll
      for (int off = 1; off < 16; off <<= 1) { sum += __shfl_xor(sum, off); sq += __shfl_xor(sq, off); }
      float mean = sum * (1.f / 128.f);
      float var = sq * (1.f / 128.f) - mean * mean;
      float rstd = rsqrtf(var + 1e-5f);
      float* orow = out + (((size_t)(bb * 256 + tg)) * 100 + rr) * 128;
#pragma unroll
      for (int ct = 0; ct < 8; ++ct)
        orow[ct * 16 + l15] = (yv[ct] - mean) * rstd * gv[ct] + bt[ct];
    }
#undef LOADW4
#undef MF8
#undef MF8C
#undef QSTORE
#undef KSTORE
#undef VSTORE
#undef OACC
}

extern "C" void kernel_launch(void* const* d_in, const int* in_sizes, int n_in,
                              void* d_out, int out_size, void* d_ws, size_t ws_size,
                              hipStream_t stream) {
  const float* x    = (const float*)d_in[0];
  const int*   mask = (const int*)d_in[1];
  const float* Wq   = (const float*)d_in[2];
  const float* bq   = (const float*)d_in[3];
  const float* Wk   = (const float*)d_in[4];
  const float* bk   = (const float*)d_in[5];
  const float* Wv   = (const float*)d_in[6];
  const float* bv   = (const float*)d_in[7];
  const float* Wp   = (const float*)d_in[8];
  const float* bp   = (const float*)d_in[9];
  const float* ln_g = (const float*)d_in[10];
  const float* ln_b = (const float*)d_in[11];
  const float* rel  = (const float*)d_in[12];
  float* out = (float*)d_out;
  u16* Wt = (u16*)d_ws;  // [4][128][128] bf16 transposed — only workspace use

  hipLaunchKernelGGL(prep_weights_kernel, dim3(4, 64), dim3(256), 0, stream, Wq, Wk, Wv, Wp, Wt);
  hipLaunchKernelGGL(fused5_kernel, dim3(400), dim3(512), 0, stream,
                     Wt, x, mask, rel, bq, bk, bv, bp, ln_g, ln_b, out);
}